// Round 4
// baseline (271.935 us; speedup 1.0000x reference)
//
#include <hip/hip_runtime.h>

// ProtoNet scores, single-GEMM formulation:
//   Z = (X - mean) @ proj            (cols 0..255 of Y)
//   U = (X - mean) @ W, W = proj@P^T (cols 256..511 of Y)  [= Z@P^T exactly]
//   inv = 1/max(||Z||,eps); z2 = ||Z||^2 * inv^2
//   out[n][c] = -sqrt(max(z2 + ||p_c||^2 - 2*U[n][c]*inv, 0))
//
// R4: the K-loop barrier is inline-asm `s_waitcnt lgkmcnt(0); s_barrier`
// (workgroup shares ONLY the A-tile via LDS, so vmcnt need not drain).
// B and X are software-pipelined 2 steps deep with alternating register
// sets (loop unrolled x2, no register copies), so every global load has
// ~2 steps of slack and the compiler emits fine-grained vmcnt(N) waits.

#define DIN     1024
#define NPROTO  256
#define BM      64
#define ASTRIDE 40                       // ushorts/row: 32 k + 8 pad (16B-aligned)
#define KT_BYTES 32768                   // 512 cols * 32 k * 2 B per k-tile

// ws layout (bytes); total 1,055,744
#define BBLOB_OFF 0                      // 32 * 32768 = 1048576
#define MVEC_OFF  1048576                // 512 f32: [mean@proj | mean@W]
#define P2_OFF    1050624                // 256 f32
#define MPART_OFF 1051648                // 4*256 f32 partial mproj

using bf16x8 = __attribute__((ext_vector_type(8))) short;
using f32x4  = __attribute__((ext_vector_type(4))) float;

struct BSet { bf16x8 v[8]; };

__device__ __forceinline__ unsigned f2bf(float f) {
  unsigned u = __float_as_uint(f);
  return (u + 0x7fffu + ((u >> 16) & 1u)) >> 16;
}

__device__ __forceinline__ uint2 pack4(float4 v) {
  return make_uint2(f2bf(v.x) | (f2bf(v.y) << 16), f2bf(v.z) | (f2bf(v.w) << 16));
}

// ---------------------------------------------------------------------------
// prep1: proj-part of blob (32 blocks) + mproj partials (16) + p2 (4) = 52
// ---------------------------------------------------------------------------
__global__ __launch_bounds__(256) void protonet_prep1(
    const float* __restrict__ mean, const float* __restrict__ proj,
    const float* __restrict__ protos, unsigned* __restrict__ Bblob,
    float* __restrict__ mpart, float* __restrict__ p2) {
  const int tid = threadIdx.x;
  const int b = blockIdx.x;
  __shared__ float plds[32 * 257];
  __shared__ float red[256];

  if (b < 32) {
    const int kt = b;
    for (int i = 0; i < 32; ++i) {
      int idx = i * 256 + tid;
      int k = idx >> 8, n = idx & 255;
      plds[k * 257 + n] = proj[(kt * 32 + k) * 256 + n];
    }
    __syncthreads();
    for (int i = 0; i < 16; ++i) {
      int idx = i * 256 + tid;
      int j = idx & 3, lane = (idx >> 2) & 63, nt = (idx >> 8) & 7, w = idx >> 11;
      int l15 = lane & 15, q = lane >> 4;
      int col = w * 128 + nt * 16 + l15;
      int kk = q * 8 + 2 * j;
      unsigned lo = f2bf(plds[kk * 257 + col]);
      unsigned hi = f2bf(plds[(kk + 1) * 257 + col]);
      Bblob[((kt * 4 + w) * 8 + nt) * 256 + lane * 4 + j] = lo | (hi << 16);
    }
  } else if (b < 48) {
    const int ib = b - 32, nb = ib & 3, ks = ib >> 2;
    const int n = nb * 64 + (tid & 63);
    const int k0 = ks * 256 + (tid >> 6) * 64;
    float s = 0.f;
    for (int k = k0; k < k0 + 64; ++k) s += mean[k] * proj[k * 256 + n];
    red[tid] = s;
    __syncthreads();
    if (tid < 64)
      mpart[ks * 256 + nb * 64 + tid] =
          red[tid] + red[tid + 64] + red[tid + 128] + red[tid + 192];
  } else {
    const int cb = b - 48;
    const int c = cb * 64 + (tid >> 2);
    const int qd = tid & 3;
    const float4* pr = (const float4*)(protos + c * 256 + qd * 64);
    float s = 0.f;
#pragma unroll
    for (int i = 0; i < 16; ++i) {
      float4 v = pr[i];
      s += v.x * v.x + v.y * v.y + v.z * v.z + v.w * v.w;
    }
    red[tid] = s;
    __syncthreads();
    if (qd == 0) p2[c] = red[tid] + red[tid + 1] + red[tid + 2] + red[tid + 3];
  }
}

// ---------------------------------------------------------------------------
// prep2: W = proj@P^T into blob (128 blocks) + mproj finalize + mW (1) = 129
// ---------------------------------------------------------------------------
__global__ __launch_bounds__(256) void protonet_prep2(
    const float* __restrict__ proj, const float* __restrict__ protos,
    unsigned* __restrict__ Bblob, float* __restrict__ mvec,
    const float* __restrict__ mpart) {
  const int tid = threadIdx.x;
  const int b = blockIdx.x;
  __shared__ float plds[32 * 256];
  __shared__ unsigned short Wl[64 * 33];

  if (b < 128) {
    const int kt = b >> 2, c0 = (b & 3) * 64;
    for (int i = 0; i < 32; ++i) {
      int idx = i * 256 + tid;
      int k = idx >> 8, n = idx & 255;
      plds[k * 256 + n] = proj[(kt * 32 + k) * 256 + n];
    }
    __syncthreads();
    const int c = c0 + (tid & 63);
    const int wv = tid >> 6;
    float acc8[8] = {0.f, 0.f, 0.f, 0.f, 0.f, 0.f, 0.f, 0.f};
    const float4* Pr = (const float4*)(protos + c * 256);
    for (int j4 = 0; j4 < 64; ++j4) {
      float4 pv = Pr[j4];
#pragma unroll
      for (int i = 0; i < 8; ++i) {
        const float4 pj = *(const float4*)&plds[(wv * 8 + i) * 256 + j4 * 4];
        acc8[i] += pj.x * pv.x + pj.y * pv.y + pj.z * pv.z + pj.w * pv.w;
      }
    }
#pragma unroll
    for (int i = 0; i < 8; ++i)
      Wl[(c - c0) * 33 + wv * 8 + i] = (unsigned short)f2bf(acc8[i]);
    __syncthreads();
    for (int i = 0; i < 4; ++i) {
      int idx = i * 256 + tid;
      int j = idx & 3, q = (idx >> 2) & 3, r = idx >> 4;
      int gc = c0 + r;
      int w = 2 + (gc >> 7);
      int cw = gc & 127;
      int nt = cw >> 4, l15 = cw & 15;
      int lane = q * 16 + l15;
      int kk = q * 8 + 2 * j;
      unsigned lo = Wl[r * 33 + kk], hi = Wl[r * 33 + kk + 1];
      Bblob[((kt * 4 + w) * 8 + nt) * 256 + lane * 4 + j] = lo | (hi << 16);
    }
  } else {
    float m = mpart[tid] + mpart[256 + tid] + mpart[512 + tid] + mpart[768 + tid];
    mvec[tid] = m;
    plds[tid] = m;
    __syncthreads();
    const float4* Pr = (const float4*)(protos + tid * 256);
    float acc = 0.f;
    for (int j4 = 0; j4 < 64; ++j4) {
      float4 pv = Pr[j4];
      const float4 mj = *(const float4*)&plds[j4 * 4];
      acc += mj.x * pv.x + mj.y * pv.y + mj.z * pv.z + mj.w * pv.w;
    }
    mvec[256 + tid] = acc;
  }
}

// ---------------------------------------------------------------------------
// main: 512 blocks x 256 thr, BM=64; wave w -> cols [128w,128w+128) of [Z|U].
// ---------------------------------------------------------------------------
__global__ __launch_bounds__(256, 2) void protonet_main(
    const float* __restrict__ X, const unsigned* __restrict__ Bblob,
    const float* __restrict__ mvec, const float* __restrict__ p2g,
    float* __restrict__ out) {
  __shared__ __align__(16) unsigned short Alds[2][BM * ASTRIDE];  // 2 x 5120 B
  __shared__ float rowsum[BM];
  __shared__ float rowinv[BM];
  __shared__ float rowz2[BM];

  const int tid = threadIdx.x;
  const int wave = tid >> 6;
  const int lane = tid & 63;
  const int l15 = lane & 15;
  const int q = lane >> 4;
  const int row0 = blockIdx.x * BM;
  const int cn = wave * 128;

  if (tid < BM) rowsum[tid] = 0.f;

  const int ar = tid >> 3;
  const int ac4 = (tid & 7) * 4;
  const float* xb = X + (row0 + ar) * DIN + ac4;
  const char* Bb = (const char*)Bblob + wave * 8192 + lane * 16;

  f32x4 acc[4][8];
#pragma unroll
  for (int mt = 0; mt < 4; ++mt)
#pragma unroll
    for (int nt = 0; nt < 8; ++nt) acc[mt][nt] = (f32x4){0.f, 0.f, 0.f, 0.f};

  // ---- pipelined prologue: A(0) staged; X(1),X(2),B(0),B(1) in flight ----
  float4 t0 = *(const float4*)(xb);
  float4 t1 = *(const float4*)(xb + 32 * DIN);
  float4 xA0 = *(const float4*)(xb + 32);
  float4 xA1 = *(const float4*)(xb + 32 * DIN + 32);
  float4 xB0 = *(const float4*)(xb + 64);
  float4 xB1 = *(const float4*)(xb + 32 * DIN + 64);
  BSet BA, BB;
#pragma unroll
  for (int nt = 0; nt < 8; ++nt) BA.v[nt] = *(const bf16x8*)(Bb + nt * 1024);
#pragma unroll
  for (int nt = 0; nt < 8; ++nt)
    BB.v[nt] = *(const bf16x8*)(Bb + KT_BYTES + nt * 1024);
  *(uint2*)&Alds[0][ar * ASTRIDE + ac4] = pack4(t0);
  *(uint2*)&Alds[0][(ar + 32) * ASTRIDE + ac4] = pack4(t1);
  asm volatile("s_waitcnt lgkmcnt(0)\n\ts_barrier" ::: "memory");

  // one K-step; on entry xp holds X(kt+1), bs holds B(kt)
  auto step = [&](int kt, float4& xp0, float4& xp1, BSet& bs) {
    // stage A(kt+1) into the other buffer (waits on xp's 2-step-old loads)
    *(uint2*)&Alds[(kt + 1) & 1][ar * ASTRIDE + ac4] = pack4(xp0);
    *(uint2*)&Alds[(kt + 1) & 1][(ar + 32) * ASTRIDE + ac4] = pack4(xp1);
    // reissue X(kt+3) into the just-freed regs
    int kx = kt + 3 <= 31 ? kt + 3 : 31;
    xp0 = *(const float4*)(xb + kx * 32);
    xp1 = *(const float4*)(xb + 32 * DIN + kx * 32);
    // A fragments from current buffer
    bf16x8 af[4];
#pragma unroll
    for (int mt = 0; mt < 4; ++mt)
      af[mt] = *(const bf16x8*)&Alds[kt & 1][(mt * 16 + l15) * ASTRIDE + q * 8];
    // compute (waits on bs's 2-step-old loads, fine-grained vmcnt)
#pragma unroll
    for (int mt = 0; mt < 4; ++mt)
#pragma unroll
      for (int nt = 0; nt < 8; ++nt)
        acc[mt][nt] = __builtin_amdgcn_mfma_f32_16x16x32_bf16(af[mt], bs.v[nt],
                                                              acc[mt][nt], 0, 0, 0);
    // reissue B(kt+2) into the just-freed set
    int kb = kt + 2 <= 31 ? kt + 2 : 31;
    const char* bsrc = Bb + kb * KT_BYTES;
#pragma unroll
    for (int nt = 0; nt < 8; ++nt) bs.v[nt] = *(const bf16x8*)(bsrc + nt * 1024);
    // LDS-only barrier: in-flight global loads survive
    asm volatile("s_waitcnt lgkmcnt(0)\n\ts_barrier" ::: "memory");
  };

  for (int kt = 0; kt < 32; kt += 2) {
    step(kt, xA0, xA1, BA);
    step(kt + 1, xB0, xB1, BB);
  }

  // ---- epilogue: center, row norms (waves 0-1 hold Z), scores (waves 2-3) ----
#pragma unroll
  for (int nt = 0; nt < 8; ++nt) {
    float mv = mvec[cn + nt * 16 + l15];
#pragma unroll
    for (int mt = 0; mt < 4; ++mt)
#pragma unroll
      for (int r = 0; r < 4; ++r) acc[mt][nt][r] -= mv;
  }

  if (wave < 2) {
#pragma unroll
    for (int mt = 0; mt < 4; ++mt)
#pragma unroll
      for (int r = 0; r < 4; ++r) {
        float ss = 0.f;
#pragma unroll
        for (int nt = 0; nt < 8; ++nt) ss += acc[mt][nt][r] * acc[mt][nt][r];
        ss += __shfl_xor(ss, 1);
        ss += __shfl_xor(ss, 2);
        ss += __shfl_xor(ss, 4);
        ss += __shfl_xor(ss, 8);
        if (l15 == 0) atomicAdd(&rowsum[mt * 16 + q * 4 + r], ss);
      }
  }
  __syncthreads();
  if (tid < BM) {
    float s = rowsum[tid];
    float inv = 1.0f / fmaxf(sqrtf(s), 1e-12f);
    rowinv[tid] = inv;
    rowz2[tid] = s * inv * inv;
  }
  __syncthreads();

  if (wave >= 2) {
#pragma unroll
    for (int nt = 0; nt < 8; ++nt) {
      int col = cn - 256 + nt * 16 + l15;
      float pp = p2g[col];
#pragma unroll
      for (int mt = 0; mt < 4; ++mt)
#pragma unroll
        for (int r = 0; r < 4; ++r) {
          int row = mt * 16 + q * 4 + r;
          float d2 = rowz2[row] + pp - 2.0f * acc[mt][nt][r] * rowinv[row];
          float sc = -sqrtf(fmaxf(d2, 0.f));
          __builtin_nontemporal_store(sc, &out[(row0 + row) * NPROTO + col]);
        }
    }
  }
}

extern "C" void kernel_launch(void* const* d_in, const int* in_sizes, int n_in,
                              void* d_out, int out_size, void* d_ws, size_t ws_size,
                              hipStream_t stream) {
  const float* X = (const float*)d_in[0];
  const float* mean = (const float*)d_in[1];
  const float* proj = (const float*)d_in[2];
  const float* protos = (const float*)d_in[3];
  float* out = (float*)d_out;

  char* ws = (char*)d_ws;  // uses 1,055,744 B
  unsigned* Bblob = (unsigned*)(ws + BBLOB_OFF);
  float* mvec = (float*)(ws + MVEC_OFF);
  float* p2 = (float*)(ws + P2_OFF);
  float* mpart = (float*)(ws + MPART_OFF);

  hipLaunchKernelGGL(protonet_prep1, dim3(52), dim3(256), 0, stream,
                     mean, proj, protos, Bblob, mpart, p2);
  hipLaunchKernelGGL(protonet_prep2, dim3(129), dim3(256), 0, stream,
                     proj, protos, Bblob, mvec, mpart);
  hipLaunchKernelGGL(protonet_main, dim3(512), dim3(256), 0, stream,
                     X, Bblob, mvec, p2, out);
}

// Round 5
// 265.523 us; speedup vs baseline: 1.0241x; 1.0241x over previous
//
#include <hip/hip_runtime.h>

// ProtoNet scores, single-GEMM formulation:
//   Z = (X - mean) @ proj            (cols 0..255 of Y)
//   U = (X - mean) @ W, W = proj@P^T (cols 256..511 of Y)  [= Z@P^T exactly]
//   inv = 1/max(||Z||,eps); z2 = ||Z||^2 * inv^2
//   out[n][c] = -sqrt(max(z2 + ||p_c||^2 - 2*U[n][c]*inv, 0))
//
// R5: BM=128 (512-thread blocks, grid=256, 1 block/CU). Waves wc and wc+4
// read IDENTICAL B fragments (served by L1), so per-CU B-delivery halves
// and total B traffic drops 512->256 MB. This tests the hypothesis that
// R2-R4's invariant 93 us is cache-hierarchy B-delivery bandwidth.

#define DIN     1024
#define NPROTO  256
#define BM      128
#define ASTRIDE 40                       // ushorts/row: 32 k + 8 pad (16B-aligned)
#define KT_BYTES 32768                   // 512 cols * 32 k * 2 B per k-tile

// ws layout (bytes); total 1,055,744
#define BBLOB_OFF 0                      // 32 * 32768 = 1048576
#define MVEC_OFF  1048576                // 512 f32: [mean@proj | mean@W]
#define P2_OFF    1050624                // 256 f32
#define MPART_OFF 1051648                // 4*256 f32 partial mproj

using bf16x8 = __attribute__((ext_vector_type(8))) short;
using f32x4  = __attribute__((ext_vector_type(4))) float;

struct BSet { bf16x8 v[8]; };

__device__ __forceinline__ unsigned f2bf(float f) {
  unsigned u = __float_as_uint(f);
  return (u + 0x7fffu + ((u >> 16) & 1u)) >> 16;
}

__device__ __forceinline__ uint2 pack4(float4 v) {
  return make_uint2(f2bf(v.x) | (f2bf(v.y) << 16), f2bf(v.z) | (f2bf(v.w) << 16));
}

// ---------------------------------------------------------------------------
// prep1: proj-part of blob (32 blocks) + mproj partials (16) + p2 (4) = 52
// ---------------------------------------------------------------------------
__global__ __launch_bounds__(256) void protonet_prep1(
    const float* __restrict__ mean, const float* __restrict__ proj,
    const float* __restrict__ protos, unsigned* __restrict__ Bblob,
    float* __restrict__ mpart, float* __restrict__ p2) {
  const int tid = threadIdx.x;
  const int b = blockIdx.x;
  __shared__ float plds[32 * 257];
  __shared__ float red[256];

  if (b < 32) {
    const int kt = b;
    for (int i = 0; i < 32; ++i) {
      int idx = i * 256 + tid;
      int k = idx >> 8, n = idx & 255;
      plds[k * 257 + n] = proj[(kt * 32 + k) * 256 + n];
    }
    __syncthreads();
    for (int i = 0; i < 16; ++i) {
      int idx = i * 256 + tid;
      int j = idx & 3, lane = (idx >> 2) & 63, nt = (idx >> 8) & 7, w = idx >> 11;
      int l15 = lane & 15, q = lane >> 4;
      int col = w * 128 + nt * 16 + l15;
      int kk = q * 8 + 2 * j;
      unsigned lo = f2bf(plds[kk * 257 + col]);
      unsigned hi = f2bf(plds[(kk + 1) * 257 + col]);
      Bblob[((kt * 4 + w) * 8 + nt) * 256 + lane * 4 + j] = lo | (hi << 16);
    }
  } else if (b < 48) {
    const int ib = b - 32, nb = ib & 3, ks = ib >> 2;
    const int n = nb * 64 + (tid & 63);
    const int k0 = ks * 256 + (tid >> 6) * 64;
    float s = 0.f;
    for (int k = k0; k < k0 + 64; ++k) s += mean[k] * proj[k * 256 + n];
    red[tid] = s;
    __syncthreads();
    if (tid < 64)
      mpart[ks * 256 + nb * 64 + tid] =
          red[tid] + red[tid + 64] + red[tid + 128] + red[tid + 192];
  } else {
    const int cb = b - 48;
    const int c = cb * 64 + (tid >> 2);
    const int qd = tid & 3;
    const float4* pr = (const float4*)(protos + c * 256 + qd * 64);
    float s = 0.f;
#pragma unroll
    for (int i = 0; i < 16; ++i) {
      float4 v = pr[i];
      s += v.x * v.x + v.y * v.y + v.z * v.z + v.w * v.w;
    }
    red[tid] = s;
    __syncthreads();
    if (qd == 0) p2[c] = red[tid] + red[tid + 1] + red[tid + 2] + red[tid + 3];
  }
}

// ---------------------------------------------------------------------------
// prep2: W = proj@P^T into blob (128 blocks) + mproj finalize + mW (1) = 129
// ---------------------------------------------------------------------------
__global__ __launch_bounds__(256) void protonet_prep2(
    const float* __restrict__ proj, const float* __restrict__ protos,
    unsigned* __restrict__ Bblob, float* __restrict__ mvec,
    const float* __restrict__ mpart) {
  const int tid = threadIdx.x;
  const int b = blockIdx.x;
  __shared__ float plds[32 * 256];
  __shared__ unsigned short Wl[64 * 33];

  if (b < 128) {
    const int kt = b >> 2, c0 = (b & 3) * 64;
    for (int i = 0; i < 32; ++i) {
      int idx = i * 256 + tid;
      int k = idx >> 8, n = idx & 255;
      plds[k * 256 + n] = proj[(kt * 32 + k) * 256 + n];
    }
    __syncthreads();
    const int c = c0 + (tid & 63);
    const int wv = tid >> 6;
    float acc8[8] = {0.f, 0.f, 0.f, 0.f, 0.f, 0.f, 0.f, 0.f};
    const float4* Pr = (const float4*)(protos + c * 256);
    for (int j4 = 0; j4 < 64; ++j4) {
      float4 pv = Pr[j4];
#pragma unroll
      for (int i = 0; i < 8; ++i) {
        const float4 pj = *(const float4*)&plds[(wv * 8 + i) * 256 + j4 * 4];
        acc8[i] += pj.x * pv.x + pj.y * pv.y + pj.z * pv.z + pj.w * pv.w;
      }
    }
#pragma unroll
    for (int i = 0; i < 8; ++i)
      Wl[(c - c0) * 33 + wv * 8 + i] = (unsigned short)f2bf(acc8[i]);
    __syncthreads();
    for (int i = 0; i < 4; ++i) {
      int idx = i * 256 + tid;
      int j = idx & 3, q = (idx >> 2) & 3, r = idx >> 4;
      int gc = c0 + r;
      int w = 2 + (gc >> 7);
      int cw = gc & 127;
      int nt = cw >> 4, l15 = cw & 15;
      int lane = q * 16 + l15;
      int kk = q * 8 + 2 * j;
      unsigned lo = Wl[r * 33 + kk], hi = Wl[r * 33 + kk + 1];
      Bblob[((kt * 4 + w) * 8 + nt) * 256 + lane * 4 + j] = lo | (hi << 16);
    }
  } else {
    float m = mpart[tid] + mpart[256 + tid] + mpart[512 + tid] + mpart[768 + tid];
    mvec[tid] = m;
    plds[tid] = m;
    __syncthreads();
    const float4* Pr = (const float4*)(protos + tid * 256);
    float acc = 0.f;
    for (int j4 = 0; j4 < 64; ++j4) {
      float4 pv = Pr[j4];
      const float4 mj = *(const float4*)&plds[j4 * 4];
      acc += mj.x * pv.x + mj.y * pv.y + mj.z * pv.z + mj.w * pv.w;
    }
    mvec[256 + tid] = acc;
  }
}

// ---------------------------------------------------------------------------
// main: 256 blocks x 512 thr, BM=128. Wave (wr=wave>>2, wc=wave&3):
// rows [64*wr, 64*wr+64), cols [128*wc, 128*wc+128) of [Z|U].
// Waves wc and wc+4 read identical B fragments (L1-served twin).
// ---------------------------------------------------------------------------
__global__ __launch_bounds__(512, 2) void protonet_main(
    const float* __restrict__ X, const unsigned* __restrict__ Bblob,
    const float* __restrict__ mvec, const float* __restrict__ p2g,
    float* __restrict__ out) {
  __shared__ __align__(16) unsigned short Alds[2][BM * ASTRIDE];  // 2 x 10240 B
  __shared__ float rowsum[BM];
  __shared__ float rowinv[BM];
  __shared__ float rowz2[BM];

  const int tid = threadIdx.x;
  const int wave = tid >> 6;
  const int wc = wave & 3;               // column group
  const int wr = wave >> 2;              // row half
  const int lane = tid & 63;
  const int l15 = lane & 15;
  const int q = lane >> 4;
  const int row0 = blockIdx.x * BM;
  const int cn = wc * 128;
  const int rbase = wr * 64;

  if (tid < BM) rowsum[tid] = 0.f;

  // A staging: thread loads rows ar and ar+64, one float4 each
  const int ar = tid >> 3;               // 0..63
  const int ac4 = (tid & 7) * 4;
  const float* xb = X + (row0 + ar) * DIN + ac4;
  const char* Bb = (const char*)Bblob + wc * 8192 + lane * 16;

  f32x4 acc[4][8];
#pragma unroll
  for (int mt = 0; mt < 4; ++mt)
#pragma unroll
    for (int nt = 0; nt < 8; ++nt) acc[mt][nt] = (f32x4){0.f, 0.f, 0.f, 0.f};

  // ---- pipelined prologue: A(0) staged; X(1),X(2),B(0),B(1) in flight ----
  float4 t0 = *(const float4*)(xb);
  float4 t1 = *(const float4*)(xb + 64 * DIN);
  float4 xA0 = *(const float4*)(xb + 32);
  float4 xA1 = *(const float4*)(xb + 64 * DIN + 32);
  float4 xB0 = *(const float4*)(xb + 64);
  float4 xB1 = *(const float4*)(xb + 64 * DIN + 64);
  BSet BA, BB;
#pragma unroll
  for (int nt = 0; nt < 8; ++nt) BA.v[nt] = *(const bf16x8*)(Bb + nt * 1024);
#pragma unroll
  for (int nt = 0; nt < 8; ++nt)
    BB.v[nt] = *(const bf16x8*)(Bb + KT_BYTES + nt * 1024);
  *(uint2*)&Alds[0][ar * ASTRIDE + ac4] = pack4(t0);
  *(uint2*)&Alds[0][(ar + 64) * ASTRIDE + ac4] = pack4(t1);
  asm volatile("s_waitcnt lgkmcnt(0)\n\ts_barrier" ::: "memory");

  // one K-step; on entry xp holds X(kt+1), bs holds B(kt)
  auto step = [&](int kt, float4& xp0, float4& xp1, BSet& bs) {
    *(uint2*)&Alds[(kt + 1) & 1][ar * ASTRIDE + ac4] = pack4(xp0);
    *(uint2*)&Alds[(kt + 1) & 1][(ar + 64) * ASTRIDE + ac4] = pack4(xp1);
    int kx = kt + 3 <= 31 ? kt + 3 : 31;
    xp0 = *(const float4*)(xb + kx * 32);
    xp1 = *(const float4*)(xb + 64 * DIN + kx * 32);
    bf16x8 af[4];
#pragma unroll
    for (int mt = 0; mt < 4; ++mt)
      af[mt] =
          *(const bf16x8*)&Alds[kt & 1][(rbase + mt * 16 + l15) * ASTRIDE + q * 8];
#pragma unroll
    for (int mt = 0; mt < 4; ++mt)
#pragma unroll
      for (int nt = 0; nt < 8; ++nt)
        acc[mt][nt] = __builtin_amdgcn_mfma_f32_16x16x32_bf16(af[mt], bs.v[nt],
                                                              acc[mt][nt], 0, 0, 0);
    int kb = kt + 2 <= 31 ? kt + 2 : 31;
    const char* bsrc = Bb + kb * KT_BYTES;
#pragma unroll
    for (int nt = 0; nt < 8; ++nt) bs.v[nt] = *(const bf16x8*)(bsrc + nt * 1024);
    asm volatile("s_waitcnt lgkmcnt(0)\n\ts_barrier" ::: "memory");
  };

  for (int kt = 0; kt < 32; kt += 2) {
    step(kt, xA0, xA1, BA);
    step(kt + 1, xB0, xB1, BB);
  }

  // ---- epilogue: center, row norms (wc<2 waves hold Z), scores (wc>=2) ----
#pragma unroll
  for (int nt = 0; nt < 8; ++nt) {
    float mv = mvec[cn + nt * 16 + l15];
#pragma unroll
    for (int mt = 0; mt < 4; ++mt)
#pragma unroll
      for (int r = 0; r < 4; ++r) acc[mt][nt][r] -= mv;
  }

  if (wc < 2) {
#pragma unroll
    for (int mt = 0; mt < 4; ++mt)
#pragma unroll
      for (int r = 0; r < 4; ++r) {
        float ss = 0.f;
#pragma unroll
        for (int nt = 0; nt < 8; ++nt) ss += acc[mt][nt][r] * acc[mt][nt][r];
        ss += __shfl_xor(ss, 1);
        ss += __shfl_xor(ss, 2);
        ss += __shfl_xor(ss, 4);
        ss += __shfl_xor(ss, 8);
        if (l15 == 0) atomicAdd(&rowsum[rbase + mt * 16 + q * 4 + r], ss);
      }
  }
  __syncthreads();
  if (tid < BM) {
    float s = rowsum[tid];
    float inv = 1.0f / fmaxf(sqrtf(s), 1e-12f);
    rowinv[tid] = inv;
    rowz2[tid] = s * inv * inv;
  }
  __syncthreads();

  if (wc >= 2) {
#pragma unroll
    for (int nt = 0; nt < 8; ++nt) {
      int col = cn - 256 + nt * 16 + l15;
      float pp = p2g[col];
#pragma unroll
      for (int mt = 0; mt < 4; ++mt)
#pragma unroll
        for (int r = 0; r < 4; ++r) {
          int row = rbase + mt * 16 + q * 4 + r;
          float d2 = rowz2[row] + pp - 2.0f * acc[mt][nt][r] * rowinv[row];
          float sc = -sqrtf(fmaxf(d2, 0.f));
          __builtin_nontemporal_store(sc, &out[(row0 + row) * NPROTO + col]);
        }
    }
  }
}

extern "C" void kernel_launch(void* const* d_in, const int* in_sizes, int n_in,
                              void* d_out, int out_size, void* d_ws, size_t ws_size,
                              hipStream_t stream) {
  const float* X = (const float*)d_in[0];
  const float* mean = (const float*)d_in[1];
  const float* proj = (const float*)d_in[2];
  const float* protos = (const float*)d_in[3];
  float* out = (float*)d_out;

  char* ws = (char*)d_ws;  // uses 1,055,744 B
  unsigned* Bblob = (unsigned*)(ws + BBLOB_OFF);
  float* mvec = (float*)(ws + MVEC_OFF);
  float* p2 = (float*)(ws + P2_OFF);
  float* mpart = (float*)(ws + MPART_OFF);

  hipLaunchKernelGGL(protonet_prep1, dim3(52), dim3(256), 0, stream,
                     mean, proj, protos, Bblob, mpart, p2);
  hipLaunchKernelGGL(protonet_prep2, dim3(129), dim3(256), 0, stream,
                     proj, protos, Bblob, mvec, mpart);
  hipLaunchKernelGGL(protonet_main, dim3(256), dim3(512), 0, stream,
                     X, Bblob, mvec, p2, out);
}